// Round 1
// baseline (536.618 us; speedup 1.0000x reference)
//
#include <hip/hip_runtime.h>
#include <hip/hip_bf16.h>

#define N_NODES 8192
#define IN_F 512
#define OUT_F 128
#define NCHUNK (N_NODES / 256)   // 32 chunks of 8 k-tiles (256 cols) each
#define LOG2E 1.4426950408889634f

typedef unsigned short u16;
typedef unsigned int u32;
typedef short s16x8 __attribute__((ext_vector_type(8)));
typedef float f32x4 __attribute__((ext_vector_type(4)));
typedef u32 u32x4 __attribute__((ext_vector_type(4)));

__device__ __forceinline__ u16 f2bf(float f) {
    union { float f; unsigned u; } x; x.f = f;
    unsigned r = x.u + 0x7FFFu + ((x.u >> 16) & 1u);
    return (u16)(r >> 16);
}

// HW pack: v_cvt_pk_bf16_f32 (rne) -> u32 (lo=a, hi=b)
__device__ __forceinline__ u32 packbf2(float a, float b) {
    __hip_bfloat162 h = __float22bfloat162_rn(make_float2(a, b));
    u32 u; __builtin_memcpy(&u, &h, 4);
    return u;
}

// edge weight: exp(sigmoid(alpha)) or 0 if masked
__device__ __forceinline__ float edge_p(float wh1, float w2, int keep) {
    float alpha = wh1 + w2;
    float e = exp2f(-LOG2E * alpha);
    float s = __builtin_amdgcn_rcpf(1.0f + e);
    float p = exp2f(LOG2E * s);
    return keep ? p : 0.0f;
}

// ---- K0: repack W [512x128] fp32 -> bf16 MFMA B-fragment layout
__global__ void repack_W(const float* __restrict__ W, u16* __restrict__ W_frag) {
    int tid = blockIdx.x * 256 + threadIdx.x;   // 0..65535
    int j = tid & 7;
    int lane = (tid >> 3) & 63;
    int nt = (tid >> 9) & 7;
    int kt = tid >> 12;
    int k = kt * 32 + (lane >> 4) * 8 + j;
    int n = nt * 16 + (lane & 15);
    W_frag[tid] = f2bf(W[k * OUT_F + n]);
}

// ---- Wa1 = W@a1, Wa2 = W@a2 (fp32, 512 each)
__global__ void compute_Wa(const float* __restrict__ W, const float* __restrict__ a1,
                           const float* __restrict__ a2,
                           float* __restrict__ Wa1, float* __restrict__ Wa2) {
    int k = blockIdx.x * 256 + threadIdx.x;
    if (k >= IN_F) return;
    float s1 = 0.f, s2 = 0.f;
    #pragma unroll 8
    for (int n = 0; n < OUT_F; n++) {
        float w = W[k * OUT_F + n];
        s1 += w * a1[n];
        s2 += w * a2[n];
    }
    Wa1[k] = s1; Wa2[k] = s2;
}

// ---- K1: h = X@W (bf16 MFMA), scatter h to B-frag layout; Wh = X@Wa (fp32).
// R5-proven shape: grid 512 blocks x 256 thr; block = 16 rows; wave w
// handles nt = 2w, 2w+1 (X rows L1-shared across the block's 4 waves).
__global__ __launch_bounds__(256)
void gemm_h(const float* __restrict__ X, const u16* __restrict__ W_frag,
            const float* __restrict__ Wa1, const float* __restrict__ Wa2,
            float* __restrict__ Wh1, float* __restrict__ Wh2,
            u16* __restrict__ h_frag) {
    int tid = threadIdx.x;
    int wave = tid >> 6;
    int lane = tid & 63;
    int quad = lane >> 4;
    int lid = lane & 15;
    int rbase = blockIdx.x * 16;
    const float* xrow = X + (size_t)(rbase + lid) * IN_F;
    const s16x8* Wf = (const s16x8*)W_frag;
    f32x4 acc0 = {}, acc1 = {};
    float p1 = 0.f, p2 = 0.f;
    int nt0 = wave * 2;

    for (int kt = 0; kt < 16; kt++) {
        int k0 = kt * 32 + quad * 8;
        float4 x0 = *(const float4*)(xrow + k0);
        float4 x1 = *(const float4*)(xrow + k0 + 4);
        u32x4 uv;
        uv.x = packbf2(x0.x, x0.y); uv.y = packbf2(x0.z, x0.w);
        uv.z = packbf2(x1.x, x1.y); uv.w = packbf2(x1.z, x1.w);
        s16x8 a = __builtin_bit_cast(s16x8, uv);
        if (wave == 0) {
            float4 wa = *(const float4*)(Wa1 + k0);
            float4 wb = *(const float4*)(Wa1 + k0 + 4);
            float4 wc = *(const float4*)(Wa2 + k0);
            float4 wd = *(const float4*)(Wa2 + k0 + 4);
            p1 += x0.x*wa.x + x0.y*wa.y + x0.z*wa.z + x0.w*wa.w
                + x1.x*wb.x + x1.y*wb.y + x1.z*wb.z + x1.w*wb.w;
            p2 += x0.x*wc.x + x0.y*wc.y + x0.z*wc.z + x0.w*wc.w
                + x1.x*wd.x + x1.y*wd.y + x1.z*wd.z + x1.w*wd.w;
        }
        s16x8 b0 = Wf[(kt * 8 + nt0) * 64 + lane];
        s16x8 b1 = Wf[(kt * 8 + nt0 + 1) * 64 + lane];
        acc0 = __builtin_amdgcn_mfma_f32_16x16x32_bf16(a, b0, acc0, 0, 0, 0);
        acc1 = __builtin_amdgcn_mfma_f32_16x16x32_bf16(a, b1, acc1, 0, 0, 0);
    }

    #pragma unroll
    for (int reg = 0; reg < 4; reg++) {
        int row = rbase + quad * 4 + reg;
        int ktile = row >> 5, kl = row & 31;
        int lane2 = (kl >> 3) * 16 + lid, j2 = kl & 7;
        h_frag[(size_t)((ktile * 8 + nt0) * 64 + lane2) * 8 + j2] = f2bf(acc0[reg]);
        h_frag[(size_t)((ktile * 8 + nt0 + 1) * 64 + lane2) * 8 + j2] = f2bf(acc1[reg]);
    }
    if (wave == 0) {
        p1 += __shfl_xor(p1, 16, 64); p1 += __shfl_xor(p1, 32, 64);
        p2 += __shfl_xor(p2, 16, 64); p2 += __shfl_xor(p2, 32, 64);
        if (lane < 16) { Wh1[rbase + lid] = p1; Wh2[rbase + lid] = p2; }
    }
}

// ---- K2: fully fused attention. 256 blocks x 512 thr (8 waves). Block owns
// 32 rows and walks the ENTIRE k-range: no out_part, no finalize.
// Per chunk (8 ktiles = 256 cols): wave w produces the edge-P A-fragments for
// ktile chunk*8+w into LDS (identity lane mapping: producer lane L writes the
// exact 16B fragment consumer lane L reads); after a raw s_barrier all waves
// consume all 8 ktiles, wave w accumulating output columns nt=w.
// Double-buffered LDS + one-chunk-ahead adj/Wh2 register prefetch that stays
// in flight across the barrier (manual lgkmcnt drain only — no vmcnt drain).
__global__ __launch_bounds__(512)
void attn_fused(const int* __restrict__ adj, const float* __restrict__ Wh1,
                const float* __restrict__ Wh2, const u16* __restrict__ h_frag,
                float* __restrict__ out) {
    __shared__ u32x4 Plds[2][8][2][64];   // [buf][ktile][rowhalf][lane] = 32 KB
    __shared__ float rsum_lds[8][32];

    int tid = threadIdx.x;
    int wave = tid >> 6;
    int lane = tid & 63;
    int quad = lane >> 4;
    int lid = lane & 15;
    int rbase = blockIdx.x * 32;
    int r0 = rbase + lid, r1 = r0 + 16;

    float wh10 = Wh1[r0], wh11 = Wh1[r1];
    f32x4 acc_lo = {}, acc_hi = {};
    float ps0 = 0.f, ps1 = 0.f;
    const s16x8* Hf = (const s16x8*)h_frag;
    const int* adjrow0 = adj + (size_t)r0 * N_NODES;
    const int* adjrow1 = adj + (size_t)r1 * N_NODES;

    // prologue: load chunk 0's tile (ktile = wave) into registers
    int k0p = wave * 32 + quad * 8;
    int4 A0a = *(const int4*)(adjrow0 + k0p);
    int4 A0b = *(const int4*)(adjrow0 + k0p + 4);
    int4 A1a = *(const int4*)(adjrow1 + k0p);
    int4 A1b = *(const int4*)(adjrow1 + k0p + 4);
    float4 W2a = *(const float4*)(Wh2 + k0p);
    float4 W2b = *(const float4*)(Wh2 + k0p + 4);

    #pragma unroll 2
    for (int c = 0; c < NCHUNK; c++) {
        // ---- produce: edge weights for ktile c*8+wave from prefetched regs
        float e0 = edge_p(wh10, W2a.x, A0a.x), e1 = edge_p(wh10, W2a.y, A0a.y);
        float e2 = edge_p(wh10, W2a.z, A0a.z), e3 = edge_p(wh10, W2a.w, A0a.w);
        float e4 = edge_p(wh10, W2b.x, A0b.x), e5 = edge_p(wh10, W2b.y, A0b.y);
        float e6 = edge_p(wh10, W2b.z, A0b.z), e7 = edge_p(wh10, W2b.w, A0b.w);
        ps0 += ((e0 + e1) + (e2 + e3)) + ((e4 + e5) + (e6 + e7));
        u32x4 uv0;
        uv0.x = packbf2(e0, e1); uv0.y = packbf2(e2, e3);
        uv0.z = packbf2(e4, e5); uv0.w = packbf2(e6, e7);

        float f0 = edge_p(wh11, W2a.x, A1a.x), f1 = edge_p(wh11, W2a.y, A1a.y);
        float f2 = edge_p(wh11, W2a.z, A1a.z), f3 = edge_p(wh11, W2a.w, A1a.w);
        float f4 = edge_p(wh11, W2b.x, A1b.x), f5 = edge_p(wh11, W2b.y, A1b.y);
        float f6 = edge_p(wh11, W2b.z, A1b.z), f7 = edge_p(wh11, W2b.w, A1b.w);
        ps1 += ((f0 + f1) + (f2 + f3)) + ((f4 + f5) + (f6 + f7));
        u32x4 uv1;
        uv1.x = packbf2(f0, f1); uv1.y = packbf2(f2, f3);
        uv1.z = packbf2(f4, f5); uv1.w = packbf2(f6, f7);

        Plds[c & 1][wave][0][lane] = uv0;
        Plds[c & 1][wave][1][lane] = uv1;

        // ---- prefetch next chunk's adj + Wh2 (clamped; stays in flight
        //      across the barrier — only lgkm is drained below)
        int cn = (c + 1 < NCHUNK) ? c + 1 : c;
        int k0n = (cn * 8 + wave) * 32 + quad * 8;
        A0a = *(const int4*)(adjrow0 + k0n);
        A0b = *(const int4*)(adjrow0 + k0n + 4);
        A1a = *(const int4*)(adjrow1 + k0n);
        A1b = *(const int4*)(adjrow1 + k0n + 4);
        W2a = *(const float4*)(Wh2 + k0n);
        W2b = *(const float4*)(Wh2 + k0n + 4);

        // make our ds_writes visible, then raw barrier (no vmcnt drain)
        asm volatile("s_waitcnt lgkmcnt(0)" ::: "memory");
        __builtin_amdgcn_s_barrier();
        asm volatile("" ::: "memory");
        __builtin_amdgcn_sched_barrier(0);

        // ---- consume: all 8 ktiles of this chunk, output slice nt = wave
        #pragma unroll
        for (int j = 0; j < 8; j++) {
            s16x8 af0 = __builtin_bit_cast(s16x8, Plds[c & 1][j][0][lane]);
            s16x8 af1 = __builtin_bit_cast(s16x8, Plds[c & 1][j][1][lane]);
            s16x8 b = Hf[((c * 8 + j) * 8 + wave) * 64 + lane];
            acc_lo = __builtin_amdgcn_mfma_f32_16x16x32_bf16(af0, b, acc_lo, 0, 0, 0);
            acc_hi = __builtin_amdgcn_mfma_f32_16x16x32_bf16(af1, b, acc_hi, 0, 0, 0);
        }
        // note: no second barrier needed — produce(c+2) reuses this buffer
        // only after barrier(c+1), which every wave reaches only after its
        // consume(c) LDS reads have drained (lgkmcnt(0) above).
    }

    // ---- row sums: reduce across quads, then across the 8 waves via LDS
    ps0 += __shfl_xor(ps0, 16, 64); ps0 += __shfl_xor(ps0, 32, 64);
    ps1 += __shfl_xor(ps1, 16, 64); ps1 += __shfl_xor(ps1, 32, 64);
    if (lane < 16) {
        rsum_lds[wave][lane] = ps0;
        rsum_lds[wave][lane + 16] = ps1;
    }
    __syncthreads();

    #pragma unroll
    for (int reg = 0; reg < 4; reg++) {
        int row = quad * 4 + reg;
        float slo = 0.f, shi = 0.f;
        #pragma unroll
        for (int w = 0; w < 8; w++) {
            slo += rsum_lds[w][row];
            shi += rsum_lds[w][row + 16];
        }
        out[(size_t)(rbase + row) * OUT_F + wave * 16 + lid] = acc_lo[reg] / slo;
        out[(size_t)(rbase + row + 16) * OUT_F + wave * 16 + lid] = acc_hi[reg] / shi;
    }
}

extern "C" void kernel_launch(void* const* d_in, const int* in_sizes, int n_in,
                              void* d_out, int out_size, void* d_ws, size_t ws_size,
                              hipStream_t stream) {
    const float* X   = (const float*)d_in[0];
    const int*   adj = (const int*)d_in[1];
    const float* W   = (const float*)d_in[2];
    const float* a1  = (const float*)d_in[3];
    const float* a2  = (const float*)d_in[4];

    char* ws = (char*)d_ws;
    float* Wh1 = (float*)(ws);                         // 32 KB
    float* Wh2 = (float*)(ws + (32 << 10));            // 32 KB
    float* Wa1 = (float*)(ws + (64 << 10));            // 2 KB
    float* Wa2 = (float*)(ws + (66 << 10));            // 2 KB
    u16* W_frag = (u16*)(ws + (128 << 10));            // 128 KB
    u16* h_frag = (u16*)(ws + (256 << 10));            // 2 MB
    float* out = (float*)d_out;

    hipLaunchKernelGGL(repack_W, dim3(256), dim3(256), 0, stream, W, W_frag);
    hipLaunchKernelGGL(compute_Wa, dim3(2), dim3(256), 0, stream, W, a1, a2, Wa1, Wa2);
    hipLaunchKernelGGL(gemm_h, dim3(512), dim3(256), 0, stream,
                       X, W_frag, Wa1, Wa2, Wh1, Wh2, h_frag);
    hipLaunchKernelGGL(attn_fused, dim3(N_NODES / 32), dim3(512), 0, stream,
                       adj, Wh1, Wh2, h_frag, out);
}

// Round 2
// 459.586 us; speedup vs baseline: 1.1676x; 1.1676x over previous
//
#include <hip/hip_runtime.h>
#include <hip/hip_bf16.h>

#define N_NODES 8192
#define IN_F 512
#define OUT_F 128
#define NWAVE 16                  // waves per block = k-partitions
#define KT_PER (256 / NWAVE)      // 16 k-tiles of 32 cols per wave
#define LOG2E 1.4426950408889634f

typedef unsigned short u16;
typedef unsigned int u32;
typedef short s16x8 __attribute__((ext_vector_type(8)));
typedef float f32x4 __attribute__((ext_vector_type(4)));
typedef u32 u32x4 __attribute__((ext_vector_type(4)));

__device__ __forceinline__ u16 f2bf(float f) {
    union { float f; unsigned u; } x; x.f = f;
    unsigned r = x.u + 0x7FFFu + ((x.u >> 16) & 1u);
    return (u16)(r >> 16);
}

// HW pack: v_cvt_pk_bf16_f32 (rne) -> u32 (lo=a, hi=b)
__device__ __forceinline__ u32 packbf2(float a, float b) {
    __hip_bfloat162 h = __float22bfloat162_rn(make_float2(a, b));
    u32 u; __builtin_memcpy(&u, &h, 4);
    return u;
}

// edge weight: exp(sigmoid(alpha)) or 0 if masked
__device__ __forceinline__ float edge_p(float wh1, float w2, int keep) {
    float alpha = wh1 + w2;
    float e = exp2f(-LOG2E * alpha);
    float s = __builtin_amdgcn_rcpf(1.0f + e);
    float p = exp2f(LOG2E * s);
    return keep ? p : 0.0f;
}

// ---- K0: repack W [512x128] fp32 -> bf16 MFMA B-fragment layout
__global__ void repack_W(const float* __restrict__ W, u16* __restrict__ W_frag) {
    int tid = blockIdx.x * 256 + threadIdx.x;   // 0..65535
    int j = tid & 7;
    int lane = (tid >> 3) & 63;
    int nt = (tid >> 9) & 7;
    int kt = tid >> 12;
    int k = kt * 32 + (lane >> 4) * 8 + j;
    int n = nt * 16 + (lane & 15);
    W_frag[tid] = f2bf(W[k * OUT_F + n]);
}

// ---- Wa1 = W@a1, Wa2 = W@a2 (fp32, 512 each)
__global__ void compute_Wa(const float* __restrict__ W, const float* __restrict__ a1,
                           const float* __restrict__ a2,
                           float* __restrict__ Wa1, float* __restrict__ Wa2) {
    int k = blockIdx.x * 256 + threadIdx.x;
    if (k >= IN_F) return;
    float s1 = 0.f, s2 = 0.f;
    #pragma unroll 8
    for (int n = 0; n < OUT_F; n++) {
        float w = W[k * OUT_F + n];
        s1 += w * a1[n];
        s2 += w * a2[n];
    }
    Wa1[k] = s1; Wa2[k] = s2;
}

// ---- K1: h = X@W (bf16 MFMA), scatter h to B-frag layout; Wh = X@Wa (fp32).
// R5-proven shape: grid 512 blocks x 256 thr; block = 16 rows; wave w
// handles nt = 2w, 2w+1 (X rows L1-shared across the block's 4 waves).
__global__ __launch_bounds__(256)
void gemm_h(const float* __restrict__ X, const u16* __restrict__ W_frag,
            const float* __restrict__ Wa1, const float* __restrict__ Wa2,
            float* __restrict__ Wh1, float* __restrict__ Wh2,
            u16* __restrict__ h_frag) {
    int tid = threadIdx.x;
    int wave = tid >> 6;
    int lane = tid & 63;
    int quad = lane >> 4;
    int lid = lane & 15;
    int rbase = blockIdx.x * 16;
    const float* xrow = X + (size_t)(rbase + lid) * IN_F;
    const s16x8* Wf = (const s16x8*)W_frag;
    f32x4 acc0 = {}, acc1 = {};
    float p1 = 0.f, p2 = 0.f;
    int nt0 = wave * 2;

    for (int kt = 0; kt < 16; kt++) {
        int k0 = kt * 32 + quad * 8;
        float4 x0 = *(const float4*)(xrow + k0);
        float4 x1 = *(const float4*)(xrow + k0 + 4);
        u32x4 uv;
        uv.x = packbf2(x0.x, x0.y); uv.y = packbf2(x0.z, x0.w);
        uv.z = packbf2(x1.x, x1.y); uv.w = packbf2(x1.z, x1.w);
        s16x8 a = __builtin_bit_cast(s16x8, uv);
        if (wave == 0) {
            float4 wa = *(const float4*)(Wa1 + k0);
            float4 wb = *(const float4*)(Wa1 + k0 + 4);
            float4 wc = *(const float4*)(Wa2 + k0);
            float4 wd = *(const float4*)(Wa2 + k0 + 4);
            p1 += x0.x*wa.x + x0.y*wa.y + x0.z*wa.z + x0.w*wa.w
                + x1.x*wb.x + x1.y*wb.y + x1.z*wb.z + x1.w*wb.w;
            p2 += x0.x*wc.x + x0.y*wc.y + x0.z*wc.z + x0.w*wc.w
                + x1.x*wd.x + x1.y*wd.y + x1.z*wd.z + x1.w*wd.w;
        }
        s16x8 b0 = Wf[(kt * 8 + nt0) * 64 + lane];
        s16x8 b1 = Wf[(kt * 8 + nt0 + 1) * 64 + lane];
        acc0 = __builtin_amdgcn_mfma_f32_16x16x32_bf16(a, b0, acc0, 0, 0, 0);
        acc1 = __builtin_amdgcn_mfma_f32_16x16x32_bf16(a, b1, acc1, 0, 0, 0);
    }

    #pragma unroll
    for (int reg = 0; reg < 4; reg++) {
        int row = rbase + quad * 4 + reg;
        int ktile = row >> 5, kl = row & 31;
        int lane2 = (kl >> 3) * 16 + lid, j2 = kl & 7;
        h_frag[(size_t)((ktile * 8 + nt0) * 64 + lane2) * 8 + j2] = f2bf(acc0[reg]);
        h_frag[(size_t)((ktile * 8 + nt0 + 1) * 64 + lane2) * 8 + j2] = f2bf(acc1[reg]);
    }
    if (wave == 0) {
        p1 += __shfl_xor(p1, 16, 64); p1 += __shfl_xor(p1, 32, 64);
        p2 += __shfl_xor(p2, 16, 64); p2 += __shfl_xor(p2, 32, 64);
        if (lane < 16) { Wh1[rbase + lid] = p1; Wh2[rbase + lid] = p2; }
    }
}

// ---- K2: fused attention, barrier-free k-sweep. 256 blocks x 1024 thr.
// Block owns 32 rows; wave w independently processes k-stripe
// [w*512, w*512+512) with the R0/R9-proven inner loop (register prefetch,
// 8-nt accumulators, NO synchronization). At the end: log2(16)-stage LDS
// tree reduction of the 16 waves' accumulators + rowsums, wave 0 divides
// and writes the final output. No out_part / sum_part / finalize.
__global__ __launch_bounds__(1024, 4)
void attn_fused(const int* __restrict__ adj, const float* __restrict__ Wh1,
                const float* __restrict__ Wh2, const u16* __restrict__ h_frag,
                float* __restrict__ out) {
    __shared__ f32x4 red[8][16][64];     // 128 KB tree-reduction buffer
    __shared__ float rsum_lds[NWAVE][32];

    int tid = threadIdx.x;
    int wave = tid >> 6;
    int lane = tid & 63;
    int quad = lane >> 4;
    int lid = lane & 15;
    int rbase = blockIdx.x * 32;
    int r0 = rbase + lid, r1 = r0 + 16;

    float wh10 = Wh1[r0], wh11 = Wh1[r1];
    f32x4 acc0[8] = {}, acc1[8] = {};
    float ps0 = 0.f, ps1 = 0.f;
    const s16x8* Hf = (const s16x8*)h_frag;
    const int* adjrow0 = adj + (size_t)r0 * N_NODES;
    const int* adjrow1 = adj + (size_t)r1 * N_NODES;

    const int kt0 = wave * KT_PER;
    const int ktend = kt0 + KT_PER;

    // prefetch prologue: first iteration's adj tiles
    int kpf = kt0 * 32 + quad * 8;
    int4 A0a = *(const int4*)(adjrow0 + kpf);
    int4 A0b = *(const int4*)(adjrow0 + kpf + 4);
    int4 A1a = *(const int4*)(adjrow1 + kpf);
    int4 A1b = *(const int4*)(adjrow1 + kpf + 4);

    #pragma unroll 1
    for (int kt = kt0; kt < ktend; kt++) {
        int k0 = kt * 32 + quad * 8;
        // consume current, issue next-iteration loads immediately
        int4 aj0a = A0a, aj0b = A0b, aj1a = A1a, aj1b = A1b;
        int ktn = (kt + 1 < ktend) ? (kt + 1) : kt;   // clamp (no OOB)
        int k0n = ktn * 32 + quad * 8;
        A0a = *(const int4*)(adjrow0 + k0n);
        A0b = *(const int4*)(adjrow0 + k0n + 4);
        A1a = *(const int4*)(adjrow1 + k0n);
        A1b = *(const int4*)(adjrow1 + k0n + 4);

        float4 w20 = *(const float4*)(Wh2 + k0);
        float4 w21 = *(const float4*)(Wh2 + k0 + 4);

        float e0 = edge_p(wh10, w20.x, aj0a.x), e1 = edge_p(wh10, w20.y, aj0a.y);
        float e2 = edge_p(wh10, w20.z, aj0a.z), e3 = edge_p(wh10, w20.w, aj0a.w);
        float e4 = edge_p(wh10, w21.x, aj0b.x), e5 = edge_p(wh10, w21.y, aj0b.y);
        float e6 = edge_p(wh10, w21.z, aj0b.z), e7 = edge_p(wh10, w21.w, aj0b.w);
        ps0 += ((e0 + e1) + (e2 + e3)) + ((e4 + e5) + (e6 + e7));
        u32x4 uv0;
        uv0.x = packbf2(e0, e1); uv0.y = packbf2(e2, e3);
        uv0.z = packbf2(e4, e5); uv0.w = packbf2(e6, e7);

        float f0 = edge_p(wh11, w20.x, aj1a.x), f1 = edge_p(wh11, w20.y, aj1a.y);
        float f2 = edge_p(wh11, w20.z, aj1a.z), f3 = edge_p(wh11, w20.w, aj1a.w);
        float f4 = edge_p(wh11, w21.x, aj1b.x), f5 = edge_p(wh11, w21.y, aj1b.y);
        float f6 = edge_p(wh11, w21.z, aj1b.z), f7 = edge_p(wh11, w21.w, aj1b.w);
        ps1 += ((f0 + f1) + (f2 + f3)) + ((f4 + f5) + (f6 + f7));
        u32x4 uv1;
        uv1.x = packbf2(f0, f1); uv1.y = packbf2(f2, f3);
        uv1.z = packbf2(f4, f5); uv1.w = packbf2(f6, f7);

        s16x8 af0 = __builtin_bit_cast(s16x8, uv0);
        s16x8 af1 = __builtin_bit_cast(s16x8, uv1);

        #pragma unroll
        for (int nt = 0; nt < 8; nt++) {
            s16x8 b = Hf[(kt * 8 + nt) * 64 + lane];
            acc0[nt] = __builtin_amdgcn_mfma_f32_16x16x32_bf16(af0, b, acc0[nt], 0, 0, 0);
            acc1[nt] = __builtin_amdgcn_mfma_f32_16x16x32_bf16(af1, b, acc1[nt], 0, 0, 0);
        }
    }

    // intra-wave rowsum reduce: lanes 0..15 hold rows r0, r1 sums
    ps0 += __shfl_xor(ps0, 16, 64); ps0 += __shfl_xor(ps0, 32, 64);
    ps1 += __shfl_xor(ps1, 16, 64); ps1 += __shfl_xor(ps1, 32, 64);
    if (lane < 16) {
        rsum_lds[wave][lane] = ps0;
        rsum_lds[wave][lane + 16] = ps1;
    }

    // ---- cross-wave tree reduction of the 16 f32x4 accumulators.
    // Stage s: waves [s,2s) park their accs in red[wave-s]; waves [0,s) add.
    // Layout [idx][v][lane] -> lane-contiguous 16B, conflict-free.
    #pragma unroll
    for (int s = 8; s >= 1; s >>= 1) {
        if (wave >= s && wave < 2 * s) {
            #pragma unroll
            for (int nt = 0; nt < 8; nt++) {
                red[wave - s][nt][lane] = acc0[nt];
                red[wave - s][nt + 8][lane] = acc1[nt];
            }
        }
        __syncthreads();
        if (wave < s) {
            #pragma unroll
            for (int nt = 0; nt < 8; nt++) {
                acc0[nt] += red[wave][nt][lane];
                acc1[nt] += red[wave][nt + 8][lane];
            }
        }
        __syncthreads();
    }

    // ---- wave 0 holds the full 32x128 tile: divide by rowsums, write out
    if (wave == 0) {
        #pragma unroll
        for (int reg = 0; reg < 4; reg++) {
            int row = quad * 4 + reg;
            float slo = 0.f, shi = 0.f;
            #pragma unroll
            for (int w = 0; w < NWAVE; w++) {
                slo += rsum_lds[w][row];
                shi += rsum_lds[w][row + 16];
            }
            float rlo = __builtin_amdgcn_rcpf(slo);
            float rhi = __builtin_amdgcn_rcpf(shi);
            // refine rcp to full precision (Newton) to keep absmax tight
            rlo = rlo * (2.0f - slo * rlo);
            rhi = rhi * (2.0f - shi * rhi);
            #pragma unroll
            for (int nt = 0; nt < 8; nt++) {
                out[(size_t)(rbase + row) * OUT_F + nt * 16 + lid] = acc0[nt][reg] * rlo;
                out[(size_t)(rbase + row + 16) * OUT_F + nt * 16 + lid] = acc1[nt][reg] * rhi;
            }
        }
    }
}

extern "C" void kernel_launch(void* const* d_in, const int* in_sizes, int n_in,
                              void* d_out, int out_size, void* d_ws, size_t ws_size,
                              hipStream_t stream) {
    const float* X   = (const float*)d_in[0];
    const int*   adj = (const int*)d_in[1];
    const float* W   = (const float*)d_in[2];
    const float* a1  = (const float*)d_in[3];
    const float* a2  = (const float*)d_in[4];

    char* ws = (char*)d_ws;
    float* Wh1 = (float*)(ws);                         // 32 KB
    float* Wh2 = (float*)(ws + (32 << 10));            // 32 KB
    float* Wa1 = (float*)(ws + (64 << 10));            // 2 KB
    float* Wa2 = (float*)(ws + (66 << 10));            // 2 KB
    u16* W_frag = (u16*)(ws + (128 << 10));            // 128 KB
    u16* h_frag = (u16*)(ws + (256 << 10));            // 2 MB
    float* out = (float*)d_out;

    hipLaunchKernelGGL(repack_W, dim3(256), dim3(256), 0, stream, W, W_frag);
    hipLaunchKernelGGL(compute_Wa, dim3(2), dim3(256), 0, stream, W, a1, a2, Wa1, Wa2);
    hipLaunchKernelGGL(gemm_h, dim3(512), dim3(256), 0, stream,
                       X, W_frag, Wa1, Wa2, Wh1, Wh2, h_frag);
    hipLaunchKernelGGL(attn_fused, dim3(N_NODES / 32), dim3(1024), 0, stream,
                       adj, Wh1, Wh2, h_frag, out);
}

// Round 3
// 430.725 us; speedup vs baseline: 1.2458x; 1.0670x over previous
//
#include <hip/hip_runtime.h>
#include <hip/hip_bf16.h>

#define N_NODES 8192
#define IN_F 512
#define OUT_F 128
#define NSTRIPE 8                 // k-stripes per block (waves = 8 stripes x 2 row-halves)
#define KT_PER 32                 // k-tiles of 32 cols per stripe
#define LOG2E 1.4426950408889634f

typedef unsigned short u16;
typedef unsigned int u32;
typedef short s16x8 __attribute__((ext_vector_type(8)));
typedef float f32x4 __attribute__((ext_vector_type(4)));
typedef u32 u32x4 __attribute__((ext_vector_type(4)));

__device__ __forceinline__ u16 f2bf(float f) {
    union { float f; unsigned u; } x; x.f = f;
    unsigned r = x.u + 0x7FFFu + ((x.u >> 16) & 1u);
    return (u16)(r >> 16);
}

// HW pack: v_cvt_pk_bf16_f32 (rne) -> u32 (lo=a, hi=b)
__device__ __forceinline__ u32 packbf2(float a, float b) {
    __hip_bfloat162 h = __float22bfloat162_rn(make_float2(a, b));
    u32 u; __builtin_memcpy(&u, &h, 4);
    return u;
}

// edge weight: exp(sigmoid(alpha)) or 0 if masked
__device__ __forceinline__ float edge_p(float wh1, float w2, int keep) {
    float alpha = wh1 + w2;
    float e = exp2f(-LOG2E * alpha);
    float s = __builtin_amdgcn_rcpf(1.0f + e);
    float p = exp2f(LOG2E * s);
    return keep ? p : 0.0f;
}

// ---- K0: repack W [512x128] fp32 -> bf16 MFMA B-fragment layout
__global__ void repack_W(const float* __restrict__ W, u16* __restrict__ W_frag) {
    int tid = blockIdx.x * 256 + threadIdx.x;   // 0..65535
    int j = tid & 7;
    int lane = (tid >> 3) & 63;
    int nt = (tid >> 9) & 7;
    int kt = tid >> 12;
    int k = kt * 32 + (lane >> 4) * 8 + j;
    int n = nt * 16 + (lane & 15);
    W_frag[tid] = f2bf(W[k * OUT_F + n]);
}

// ---- Wa1 = W@a1, Wa2 = W@a2 (fp32, 512 each)
__global__ void compute_Wa(const float* __restrict__ W, const float* __restrict__ a1,
                           const float* __restrict__ a2,
                           float* __restrict__ Wa1, float* __restrict__ Wa2) {
    int k = blockIdx.x * 256 + threadIdx.x;
    if (k >= IN_F) return;
    float s1 = 0.f, s2 = 0.f;
    #pragma unroll 8
    for (int n = 0; n < OUT_F; n++) {
        float w = W[k * OUT_F + n];
        s1 += w * a1[n];
        s2 += w * a2[n];
    }
    Wa1[k] = s1; Wa2[k] = s2;
}

// ---- K1: h = X@W (bf16 MFMA), scatter h to B-frag layout; Wh = X@Wa (fp32).
__global__ __launch_bounds__(256)
void gemm_h(const float* __restrict__ X, const u16* __restrict__ W_frag,
            const float* __restrict__ Wa1, const float* __restrict__ Wa2,
            float* __restrict__ Wh1, float* __restrict__ Wh2,
            u16* __restrict__ h_frag) {
    int tid = threadIdx.x;
    int wave = tid >> 6;
    int lane = tid & 63;
    int quad = lane >> 4;
    int lid = lane & 15;
    int rbase = blockIdx.x * 16;
    const float* xrow = X + (size_t)(rbase + lid) * IN_F;
    const s16x8* Wf = (const s16x8*)W_frag;
    f32x4 acc0 = {}, acc1 = {};
    float p1 = 0.f, p2 = 0.f;
    int nt0 = wave * 2;

    for (int kt = 0; kt < 16; kt++) {
        int k0 = kt * 32 + quad * 8;
        float4 x0 = *(const float4*)(xrow + k0);
        float4 x1 = *(const float4*)(xrow + k0 + 4);
        u32x4 uv;
        uv.x = packbf2(x0.x, x0.y); uv.y = packbf2(x0.z, x0.w);
        uv.z = packbf2(x1.x, x1.y); uv.w = packbf2(x1.z, x1.w);
        s16x8 a = __builtin_bit_cast(s16x8, uv);
        if (wave == 0) {
            float4 wa = *(const float4*)(Wa1 + k0);
            float4 wb = *(const float4*)(Wa1 + k0 + 4);
            float4 wc = *(const float4*)(Wa2 + k0);
            float4 wd = *(const float4*)(Wa2 + k0 + 4);
            p1 += x0.x*wa.x + x0.y*wa.y + x0.z*wa.z + x0.w*wa.w
                + x1.x*wb.x + x1.y*wb.y + x1.z*wb.z + x1.w*wb.w;
            p2 += x0.x*wc.x + x0.y*wc.y + x0.z*wc.z + x0.w*wc.w
                + x1.x*wd.x + x1.y*wd.y + x1.z*wd.z + x1.w*wd.w;
        }
        s16x8 b0 = Wf[(kt * 8 + nt0) * 64 + lane];
        s16x8 b1 = Wf[(kt * 8 + nt0 + 1) * 64 + lane];
        acc0 = __builtin_amdgcn_mfma_f32_16x16x32_bf16(a, b0, acc0, 0, 0, 0);
        acc1 = __builtin_amdgcn_mfma_f32_16x16x32_bf16(a, b1, acc1, 0, 0, 0);
    }

    #pragma unroll
    for (int reg = 0; reg < 4; reg++) {
        int row = rbase + quad * 4 + reg;
        int ktile = row >> 5, kl = row & 31;
        int lane2 = (kl >> 3) * 16 + lid, j2 = kl & 7;
        h_frag[(size_t)((ktile * 8 + nt0) * 64 + lane2) * 8 + j2] = f2bf(acc0[reg]);
        h_frag[(size_t)((ktile * 8 + nt0 + 1) * 64 + lane2) * 8 + j2] = f2bf(acc1[reg]);
    }
    if (wave == 0) {
        p1 += __shfl_xor(p1, 16, 64); p1 += __shfl_xor(p1, 32, 64);
        p2 += __shfl_xor(p2, 16, 64); p2 += __shfl_xor(p2, 32, 64);
        if (lane < 16) { Wh1[rbase + lid] = p1; Wh2[rbase + lid] = p2; }
    }
}

// ---- K2: fused attention. 256 blocks x 1024 thr = 16 waves.
// wave = (stripe p, row-half h): 16 rows, 1024-col k-stripe, barrier-free
// k-sweep with depth-1 register prefetch of adj AND Wh2.
// KEY CHANGE (R3): per-block k-phase ROTATION — blocks start their sweep at
// phase=(blockIdx*11)&31 and wrap. This decorrelates the low address bits of
// the adj stream grid-wide (row stride is 32KB, so without rotation all
// concurrent accesses cluster into a few 128B column windows -> few active
// HBM channels -> the 844 GB/s cap seen in R2).
// End: park accs in LDS once, each wave finalizes one (h, nt) slice.
__global__ __launch_bounds__(1024, 4)
void attn_fused(const int* __restrict__ adj, const float* __restrict__ Wh1,
                const float* __restrict__ Wh2, const u16* __restrict__ h_frag,
                float* __restrict__ out) {
    __shared__ f32x4 red[16][8][64];        // 128 KB acc-park buffer
    __shared__ float rsum_lds[NSTRIPE][32]; // 1 KB rowsums

    int tid = threadIdx.x;
    int wave = tid >> 6;
    int lane = tid & 63;
    int quad = lane >> 4;
    int lid = lane & 15;
    int p = wave >> 1;          // k-stripe 0..7
    int h = wave & 1;           // row half 0..1
    int rbase = blockIdx.x * 32;
    int r0 = rbase + h * 16 + lid;

    float wh10 = Wh1[r0];
    f32x4 acc[8] = {};
    float ps0 = 0.f;
    const s16x8* Hf = (const s16x8*)h_frag;
    const int* adjrow0 = adj + (size_t)r0 * N_NODES;

    const int kt0 = p * KT_PER;
    const int phase = (blockIdx.x * 11) & (KT_PER - 1);

    // prologue: prefetch iteration 0's adj + Wh2
    int ktc = kt0 + phase;
    int kpf = ktc * 32 + quad * 8;
    int4 A0a = *(const int4*)(adjrow0 + kpf);
    int4 A0b = *(const int4*)(adjrow0 + kpf + 4);
    float4 W2a = *(const float4*)(Wh2 + kpf);
    float4 W2b = *(const float4*)(Wh2 + kpf + 4);

    #pragma unroll 1
    for (int i = 0; i < KT_PER; i++) {
        int kt = kt0 + ((i + phase) & (KT_PER - 1));
        // consume current, issue next-iteration loads immediately
        int4 aj0a = A0a, aj0b = A0b;
        float4 w20 = W2a, w21 = W2b;
        int ktn = kt0 + ((i + 1 + phase) & (KT_PER - 1));   // wrap (no OOB)
        int k0n = ktn * 32 + quad * 8;
        A0a = *(const int4*)(adjrow0 + k0n);
        A0b = *(const int4*)(adjrow0 + k0n + 4);
        W2a = *(const float4*)(Wh2 + k0n);
        W2b = *(const float4*)(Wh2 + k0n + 4);

        float e0 = edge_p(wh10, w20.x, aj0a.x), e1 = edge_p(wh10, w20.y, aj0a.y);
        float e2 = edge_p(wh10, w20.z, aj0a.z), e3 = edge_p(wh10, w20.w, aj0a.w);
        float e4 = edge_p(wh10, w21.x, aj0b.x), e5 = edge_p(wh10, w21.y, aj0b.y);
        float e6 = edge_p(wh10, w21.z, aj0b.z), e7 = edge_p(wh10, w21.w, aj0b.w);
        ps0 += ((e0 + e1) + (e2 + e3)) + ((e4 + e5) + (e6 + e7));
        u32x4 uv0;
        uv0.x = packbf2(e0, e1); uv0.y = packbf2(e2, e3);
        uv0.z = packbf2(e4, e5); uv0.w = packbf2(e6, e7);
        s16x8 af0 = __builtin_bit_cast(s16x8, uv0);

        #pragma unroll
        for (int nt = 0; nt < 8; nt++) {
            s16x8 b = Hf[(kt * 8 + nt) * 64 + lane];
            acc[nt] = __builtin_amdgcn_mfma_f32_16x16x32_bf16(af0, b, acc[nt], 0, 0, 0);
        }
    }

    // rowsum: reduce across quads; lanes 0..15 hold this wave's 16 rows
    ps0 += __shfl_xor(ps0, 16, 64); ps0 += __shfl_xor(ps0, 32, 64);
    if (lane < 16) rsum_lds[p][h * 16 + lane] = ps0;

    // park accumulators (one write per wave), single barrier
    #pragma unroll
    for (int nt = 0; nt < 8; nt++) red[wave][nt][lane] = acc[nt];
    __syncthreads();

    // finalize: wave handles slice (h2 = wave&1, nt2 = wave>>1):
    // sum the 8 stripes' accs + rowsums, divide, write final out
    int h2 = wave & 1, nt2 = wave >> 1;
    f32x4 s = red[h2][nt2][lane];               // stripe 0 (wave idx = 0*2+h2)
    #pragma unroll
    for (int p2 = 1; p2 < NSTRIPE; p2++) s += red[p2 * 2 + h2][nt2][lane];

    #pragma unroll
    for (int reg = 0; reg < 4; reg++) {
        int rowl = quad * 4 + reg;
        float sum = 0.f;
        #pragma unroll
        for (int p2 = 0; p2 < NSTRIPE; p2++) sum += rsum_lds[p2][h2 * 16 + rowl];
        float r = __builtin_amdgcn_rcpf(sum);
        r = r * (2.0f - sum * r);               // Newton refine
        out[(size_t)(rbase + h2 * 16 + rowl) * OUT_F + nt2 * 16 + lid] = s[reg] * r;
    }
}

extern "C" void kernel_launch(void* const* d_in, const int* in_sizes, int n_in,
                              void* d_out, int out_size, void* d_ws, size_t ws_size,
                              hipStream_t stream) {
    const float* X   = (const float*)d_in[0];
    const int*   adj = (const int*)d_in[1];
    const float* W   = (const float*)d_in[2];
    const float* a1  = (const float*)d_in[3];
    const float* a2  = (const float*)d_in[4];

    char* ws = (char*)d_ws;
    float* Wh1 = (float*)(ws);                         // 32 KB
    float* Wh2 = (float*)(ws + (32 << 10));            // 32 KB
    float* Wa1 = (float*)(ws + (64 << 10));            // 2 KB
    float* Wa2 = (float*)(ws + (66 << 10));            // 2 KB
    u16* W_frag = (u16*)(ws + (128 << 10));            // 128 KB
    u16* h_frag = (u16*)(ws + (256 << 10));            // 2 MB
    float* out = (float*)d_out;

    hipLaunchKernelGGL(repack_W, dim3(256), dim3(256), 0, stream, W, W_frag);
    hipLaunchKernelGGL(compute_Wa, dim3(2), dim3(256), 0, stream, W, a1, a2, Wa1, Wa2);
    hipLaunchKernelGGL(gemm_h, dim3(512), dim3(256), 0, stream,
                       X, W_frag, Wa1, Wa2, Wh1, Wh2, h_frag);
    hipLaunchKernelGGL(attn_fused, dim3(N_NODES / 32), dim3(1024), 0, stream,
                       adj, Wh1, Wh2, h_frag, out);
}